// Round 1
// baseline (337.075 us; speedup 1.0000x reference)
//
#include <hip/hip_runtime.h>

// VectorQuantizer forward: out = codebook[argmin_k ||x - e_k||^2] (straight-through value)
// inputs:  d_in[0] = inputs  [32,64,64,64] fp32  (N=131072 rows, D=64)
//          d_in[1] = embeddings [64,512] fp32    (D=64, K=512)
// out:     [32,64,64,64] fp32

#define KC 512
#define DD 64

// Precompute E^T (K x D, row-contiguous) and bias_k = ||e_k||^2 into workspace.
__global__ void vq_prep(const float* __restrict__ emb,
                        float* __restrict__ et, float* __restrict__ bias) {
    int k = blockIdx.x * blockDim.x + threadIdx.x;
    if (k >= KC) return;
    float s = 0.f;
    #pragma unroll
    for (int d = 0; d < DD; ++d) {
        float v = emb[d * KC + k];
        et[k * DD + d] = v;
        s += v * v;
    }
    bias[k] = s;
}

// One thread per row. x[64] in VGPRs; e_k streamed via wave-uniform scalar loads.
__global__ __launch_bounds__(256) void vq_main(const float* __restrict__ x_in,
                                               const float* __restrict__ et,
                                               const float* __restrict__ bias,
                                               float* __restrict__ out) {
    const int row = blockIdx.x * 256 + threadIdx.x;

    float x[DD];
    {
        const float4* xin4 = (const float4*)(x_in + (size_t)row * DD);
        #pragma unroll
        for (int i = 0; i < DD / 4; ++i) {
            float4 v = xin4[i];
            x[4 * i + 0] = v.x;
            x[4 * i + 1] = v.y;
            x[4 * i + 2] = v.z;
            x[4 * i + 3] = v.w;
        }
    }

    float minv = 3.4e38f;
    int mink = 0;

    #pragma unroll 2
    for (int k = 0; k < KC; ++k) {
        const float* ek = et + k * DD;   // wave-uniform address -> s_load
        float a0 = 0.f, a1 = 0.f, a2 = 0.f, a3 = 0.f;
        #pragma unroll
        for (int d = 0; d < DD; d += 4) {
            a0 += x[d + 0] * ek[d + 0];
            a1 += x[d + 1] * ek[d + 1];
            a2 += x[d + 2] * ek[d + 2];
            a3 += x[d + 3] * ek[d + 3];
        }
        float dot = (a0 + a1) + (a2 + a3);
        float s = bias[k] - 2.f * dot;   // ||x||^2 term is argmin-invariant
        if (s < minv) { minv = s; mink = k; }  // strict <: first index wins ties
    }

    // Gather the winning code and apply the straight-through arithmetic
    // out = x + (q - x)  (matches reference rounding behavior in fp32)
    const float* eq = et + mink * DD;    // per-lane address -> vector loads
    float* op = out + (size_t)row * DD;
    #pragma unroll
    for (int d = 0; d < DD; d += 4) {
        float4 q = *(const float4*)(eq + d);
        float4 o;
        o.x = x[d + 0] + (q.x - x[d + 0]);
        o.y = x[d + 1] + (q.y - x[d + 1]);
        o.z = x[d + 2] + (q.z - x[d + 2]);
        o.w = x[d + 3] + (q.w - x[d + 3]);
        *(float4*)(op + d) = o;
    }
}

extern "C" void kernel_launch(void* const* d_in, const int* in_sizes, int n_in,
                              void* d_out, int out_size, void* d_ws, size_t ws_size,
                              hipStream_t stream) {
    const float* x_in = (const float*)d_in[0];   // [131072, 64]
    const float* emb  = (const float*)d_in[1];   // [64, 512]
    float* out = (float*)d_out;

    float* et   = (float*)d_ws;                  // [512, 64]
    float* bias = et + KC * DD;                  // [512]

    const int N = out_size / DD;                 // 131072 rows

    vq_prep<<<(KC + 255) / 256, 256, 0, stream>>>(emb, et, bias);
    vq_main<<<N / 256, 256, 0, stream>>>(x_in, et, bias, out);
}